// Round 3
// baseline (73.634 us; speedup 1.0000x reference)
//
#include <hip/hip_runtime.h>

#define BB 8
#define HH 256
#define WW 256
#define NTOT (BB * HH * WW)   // 524288
#define RPB 8                 // rows per block
#define NBLK (BB * HH / RPB)  // 256 blocks
#define NPART (BB * HH / 4)   // 512 partial slots (R0-compatible layout)

// ---- Single fused kernel: per-block self-sufficient mask build ------------
// Each thread owns column j of image b and re-reads the full column (256
// coalesced loads, L2-resident: target is 2 MB, fits every XCD L2) to build
// the 256-bit foreground mask in registers. This removes the build_masks
// dispatch AND the cross-block dependency entirely -- no atomics, no fences
// (round 1/2 showed agent-scope handoff costs more than a dispatch).
// Pruning exactness: k=j gives dt2(j) <= g2(j), so any argmin k* has
// |j-k*| <= d_j; scanning |delta| <= R with R = block max of min(d,255) over
// all RPB rows is >= each row's own max -> exact. Sentinel pads kill bounds
// checks. Rows 0-3 / 4-7 accumulate into separate sets stored at the R0
// partial slots so the final summation is bitwise-identical to round 0.
__global__ __launch_bounds__(256) void fused_kernel(
    const float* __restrict__ logits, const float* __restrict__ target,
    float* __restrict__ partials /* [5][NPART] */) {
  __shared__ float s_g2[RPB][3 * WW];  // [pad | row | pad], sentinel-filled
  __shared__ float s_red[4][10];
  __shared__ int s_im[4 * 2];  // per-wave {any, rmax}

  const int g = blockIdx.x;   // 0..255
  const int b = g >> 5;       // image
  const int t = g & 31;       // row-group within image
  const int i0 = t * RPB;     // first row
  const int j = threadIdx.x;  // column
  const int lane = j & 63, wave = j >> 6;

  const float* tcol = target + b * (HH * WW) + j;
  const float* lcol = logits + b * (HH * WW) + j;

  // issue own-row elementwise inputs first: latency hides under mask build
  float xr[RPB], tr[RPB];
#pragma unroll
  for (int r = 0; r < RPB; ++r) {
    xr[r] = lcol[(i0 + r) * WW];
    tr[r] = tcol[(i0 + r) * WW];
  }

  // full-column read -> per-column 256-bit fg mask in registers
  unsigned m[8];
#pragma unroll
  for (int w = 0; w < 8; ++w) {
    float v[32];
#pragma unroll
    for (int r = 0; r < 32; ++r) v[r] = tcol[(w * 32 + r) * WW];
    unsigned mm = 0u;
#pragma unroll
    for (int r = 0; r < 32; ++r) mm |= (v[r] > 0.5f) ? (1u << r) : 0u;
    m[w] = mm;
  }
  const unsigned many = m[0] | m[1] | m[2] | m[3] | m[4] | m[5] | m[6] | m[7];

  // vertical distances for own rows; sentinel pads; track scan radius
  int rmax = 0;
#pragma unroll
  for (int r = 0; r < RPB; ++r) {
    const int i = i0 + r;
    const int wi = i >> 5, rr = i & 31;
    int dUp = 1 << 30, dDn = 1 << 30;
    const unsigned cur = m[wi] >> rr;  // bits at rows >= i
    if (cur) {
      dUp = __builtin_ctz(cur);
    } else {
      int off = 32 - rr;
      for (int w2 = wi + 1; w2 < 8; ++w2, off += 32)
        if (m[w2]) { dUp = off + __builtin_ctz(m[w2]); break; }
    }
    const unsigned curd = m[wi] << (31 - rr);  // bits at rows <= i
    if (curd) {
      dDn = __builtin_clz(curd);
    } else {
      int off = rr + 1;
      for (int w2 = wi - 1; w2 >= 0; --w2, off += 32)
        if (m[w2]) { dDn = off + __builtin_clz(m[w2]); break; }
    }
    const int d = min(dUp, dDn);
    s_g2[r][WW + j] = (d < 256) ? (float)(d * d) : 1.0e9f;
    s_g2[r][j] = 1.0e9f;           // left pad
    s_g2[r][2 * WW + j] = 1.0e9f;  // right pad
    rmax = max(rmax, min(d, 255));
  }

  const int wave_any = __any(many != 0u);
#pragma unroll
  for (int off = 32; off > 0; off >>= 1)
    rmax = max(rmax, __shfl_down(rmax, off, 64));
  if (lane == 0) { s_im[wave * 2] = wave_any; s_im[wave * 2 + 1] = rmax; }
  __syncthreads();
  const int nonempty = s_im[0] | s_im[2] | s_im[4] | s_im[6];
  const int R = max(max(s_im[1], s_im[3]), max(s_im[5], s_im[7]));

  // per-row pruned horizontal min + fused elementwise; rows 0-3 -> va,
  // rows 4-7 -> vb (preserves round-0 per-block summation order exactly)
  float va[5] = {0.f, 0.f, 0.f, 0.f, 0.f};
  float vb[5] = {0.f, 0.f, 0.f, 0.f, 0.f};
#pragma unroll
  for (int r = 0; r < RPB; ++r) {
    const float* gp = &s_g2[r][WW + j];
    float mn = gp[0];
    for (int dlt = 1; dlt <= R; ++dlt) {
      const float d2 = (float)(dlt * dlt);
      mn = fminf(mn, fminf(d2 + gp[dlt], d2 + gp[-dlt]));
    }
    const float dt = nonempty ? sqrtf(mn) : 0.0f;

    const float x = xr[r];
    float tt = tr[r];
    tt = fminf(fmaxf(tt, 0.0f), 1.0f);
    const float e = __expf(-fabsf(x));
    const float inv = 1.0f / (1.0f + e);
    const float ce = fmaxf(x, 0.0f) + __logf(1.0f + e) - x * tt;
    float p = (x >= 0.0f) ? inv : e * inv;  // sigmoid
    p = fminf(fmaxf(p, 1e-6f), 1.0f - 1e-6f);
    float* vv = (r < 4) ? va : vb;  // r is compile-time (unrolled): static
    vv[0] += ce; vv[1] += p; vv[2] += tt; vv[3] += p * tt; vv[4] += p * dt;
  }

  // block reduce (fp32): 10 sums (two 4-row groups), same tree as round 0
  float v10[10] = {va[0], va[1], va[2], va[3], va[4],
                   vb[0], vb[1], vb[2], vb[3], vb[4]};
#pragma unroll
  for (int q = 0; q < 10; ++q) {
    float s = v10[q];
#pragma unroll
    for (int off = 32; off > 0; off >>= 1) s += __shfl_down(s, off, 64);
    if (lane == 0) s_red[wave][q] = s;
  }
  __syncthreads();
  if (j == 0) {
    const int o0 = b * 64 + 2 * t;  // R0 slot for rows i0..i0+3
#pragma unroll
    for (int q = 0; q < 5; ++q) {
      partials[q * NPART + o0] =
          s_red[0][q] + s_red[1][q] + s_red[2][q] + s_red[3][q];
      partials[q * NPART + o0 + 1] =
          s_red[0][5 + q] + s_red[1][5 + q] + s_red[2][5 + q] + s_red[3][5 + q];
    }
  }
}

// ---------------- Kernel 2: final reduction (double) + loss math -----------
__global__ __launch_bounds__(256) void finalize(
    const float* __restrict__ partials, float* __restrict__ out) {
  __shared__ double s_red[4 * 5];
  const int j = threadIdx.x;  // 256 threads
  const int lane = j & 63, wave = j >> 6;
  double acc[5];
#pragma unroll
  for (int q = 0; q < 5; ++q)
    acc[q] = (double)partials[q * NPART + j] +
             (double)partials[q * NPART + 256 + j];
#pragma unroll
  for (int q = 0; q < 5; ++q) {
    double s = acc[q];
#pragma unroll
    for (int off = 32; off > 0; off >>= 1) s += __shfl_down(s, off, 64);
    if (lane == 0) s_red[wave * 5 + q] = s;
  }
  __syncthreads();
  if (j == 0) {
    double sum[5];
#pragma unroll
    for (int q = 0; q < 5; ++q)
      sum[q] = s_red[q] + s_red[5 + q] + s_red[10 + q] + s_red[15 + q];
    const double n = (double)NTOT;
    const double ce = sum[0] / n;
    const double dice = 1.0 - (2.0 * sum[3] + 1e-6) / (sum[1] + sum[2] + 1e-6);
    const double boundary = sum[4] / n;
    out[0] = (float)(ce + dice + 0.1 * boundary);
    out[1] = (float)ce;
    out[2] = (float)dice;
    out[3] = (float)boundary;
  }
}

extern "C" void kernel_launch(void* const* d_in, const int* in_sizes, int n_in,
                              void* d_out, int out_size, void* d_ws,
                              size_t ws_size, hipStream_t stream) {
  const float* logits = (const float*)d_in[0];
  const float* target = (const float*)d_in[1];
  float* out = (float*)d_out;

  float* partials = (float*)d_ws;  // 5*512*4 = 10 KB

  fused_kernel<<<NBLK, 256, 0, stream>>>(logits, target, partials);
  finalize<<<1, 256, 0, stream>>>(partials, out);
}

// Round 4
// 67.770 us; speedup vs baseline: 1.0865x; 1.0865x over previous
//
#include <hip/hip_runtime.h>

#define BB 8
#define HH 256
#define WW 256
#define NTOT (BB * HH * WW)   // 524288
#define RPB 4                 // rows per block (same as round-0 geometry)
#define NBLK (BB * HH / RPB)  // 512 blocks
#define HALO 16               // halo rows above/below the block's 4 rows
#define WLEN (RPB + 2 * HALO) // 36-row window

// ---- Single fused kernel: windowed mask build + EDT + elementwise ---------
// Each thread owns column j of its block's 4 rows and loads a 36-row window
// of target into a 64-bit register mask (edge rows predicated off). Vertical
// nearest-fg distance comes from the window when present; an empty direction
// triggers a lazy serial walk beyond the window (P ~ 2^-17 per column for
// this input -> ~1 thread/launch). Window-empty columns walk BOTH directions,
// covering the full column, so `nonempty` stays exact. All d values and all
// downstream fp ops are bit-identical to the round-0 3-dispatch version
// (same partial slots, same finalize) -> absmax 0.0 preserved.
// Occupancy matches round-0 main (512 blocks, 2/CU); round-3's regression
// (1 wave/SIMD + 272 cold loads/thread) is avoided: ~40 loads/thread.
__global__ __launch_bounds__(256) void fused_kernel(
    const float* __restrict__ logits, const float* __restrict__ target,
    float* __restrict__ partials /* [5][NBLK] */) {
  __shared__ float s_g2[RPB][3 * WW];  // [pad | row | pad], sentinel-filled
  __shared__ float s_red[4 * 5];
  __shared__ int s_im[4 * 2];  // per-wave {any, rmax}

  const int g = blockIdx.x;        // 0..511
  const int b = g >> 6;            // image
  const int i0 = (g & 63) * RPB;   // first row within image
  const int j = threadIdx.x;       // column
  const int lane = j & 63, wave = j >> 6;

  const float* tcol = target + b * (HH * WW) + j;
  const float* lcol = logits + b * (HH * WW) + j;

  // own-row elementwise inputs: issue first so HBM latency hides under the
  // window/mask phase
  float xr[RPB], tr[RPB];
#pragma unroll
  for (int r = 0; r < RPB; ++r) {
    xr[r] = lcol[(i0 + r) * WW];
    tr[r] = tcol[(i0 + r) * WW];
  }

  // 36-row window -> 64-bit fg mask; bit k = row (i0 - HALO + k).
  // Out-of-image rows: clamped (safe) load, bit predicated off. The
  // row-validity condition is block-uniform per k -> no lane divergence.
  const int base = i0 - HALO;  // may be negative
  unsigned long long w64 = 0ull;
#pragma unroll
  for (int k = 0; k < WLEN; ++k) {
    const int row = base + k;
    const int rc = min(max(row, 0), HH - 1);
    const float v = tcol[rc * WW];
    if (row >= 0 && row < HH && v > 0.5f) w64 |= (1ull << k);
  }

  // lazy exact fallbacks beyond the window (rare; per-thread serial walk)
  int fgDown = 1 << 20;    // first fg row below the window (huge if none)
  int fgUp = -(1 << 20);   // first fg row above the window (-huge if none)
  if ((w64 >> (RPB - 1 + HALO)) == 0ull) {  // no fg in [i0+3, window top]
    for (int row = i0 + RPB - 1 + HALO + 1; row < HH; ++row)
      if (tcol[row * WW] > 0.5f) { fgDown = row; break; }
  }
  if ((w64 << (63 - HALO)) == 0ull) {       // no fg in [window bottom, i0]
    for (int row = i0 - HALO - 1; row >= 0; --row)
      if (tcol[row * WW] > 0.5f) { fgUp = row; break; }
  }
  const bool found =
      (w64 != 0ull) || (fgDown < (1 << 19)) || (fgUp > -(1 << 19));

  // vertical distances for the block's rows; sentinel pads; scan radius
  int rmax = 0;
#pragma unroll
  for (int r = 0; r < RPB; ++r) {
    const int i = i0 + r;
    const int p = r + HALO;  // compile-time bit position of row i
    const unsigned long long bd = w64 >> p;          // rows >= i
    const unsigned long long bu = w64 << (63 - p);   // rows <= i
    const int dUp = bd ? __builtin_ctzll(bd) : (fgDown - i);
    const int dDn = bu ? __builtin_clzll(bu) : (i - fgUp);
    const int d = min(dUp, dDn);
    s_g2[r][WW + j] = (d < 256) ? (float)(d * d) : 1.0e9f;
    s_g2[r][j] = 1.0e9f;           // left pad
    s_g2[r][2 * WW + j] = 1.0e9f;  // right pad
    rmax = max(rmax, min(d, 255));
  }

  const int wave_any = __any(found);
#pragma unroll
  for (int off = 32; off > 0; off >>= 1)
    rmax = max(rmax, __shfl_down(rmax, off, 64));
  if (lane == 0) { s_im[wave * 2] = wave_any; s_im[wave * 2 + 1] = rmax; }
  __syncthreads();
  const int nonempty = s_im[0] | s_im[2] | s_im[4] | s_im[6];
  const int R = max(max(s_im[1], s_im[3]), max(s_im[5], s_im[7]));

  // per-row pruned exact horizontal min + fused elementwise
  // (k=j gives dt2(j) <= g2(j) => any argmin k* has |j-k*| <= d_j <= R)
  float v0 = 0.f, v1 = 0.f, v2 = 0.f, v3 = 0.f, v4 = 0.f;
#pragma unroll
  for (int r = 0; r < RPB; ++r) {
    const float* gp = &s_g2[r][WW + j];
    float mn = gp[0];
    for (int dlt = 1; dlt <= R; ++dlt) {
      const float d2 = (float)(dlt * dlt);
      mn = fminf(mn, fminf(d2 + gp[dlt], d2 + gp[-dlt]));
    }
    const float dt = nonempty ? sqrtf(mn) : 0.0f;

    const float x = xr[r];
    float t = tr[r];
    t = fminf(fmaxf(t, 0.0f), 1.0f);
    const float e = __expf(-fabsf(x));
    const float inv = 1.0f / (1.0f + e);
    const float ce = fmaxf(x, 0.0f) + __logf(1.0f + e) - x * t;
    float p = (x >= 0.0f) ? inv : e * inv;  // sigmoid
    p = fminf(fmaxf(p, 1e-6f), 1.0f - 1e-6f);
    v0 += ce; v1 += p; v2 += t; v3 += p * t; v4 += p * dt;
  }

  // block reduce (fp32) -> per-block partial stores (round-0 identical)
  float v[5] = {v0, v1, v2, v3, v4};
#pragma unroll
  for (int q = 0; q < 5; ++q) {
    float s = v[q];
#pragma unroll
    for (int off = 32; off > 0; off >>= 1) s += __shfl_down(s, off, 64);
    if (lane == 0) s_red[wave * 5 + q] = s;
  }
  __syncthreads();
  if (j == 0) {
#pragma unroll
    for (int q = 0; q < 5; ++q)
      partials[q * NBLK + g] =
          s_red[q] + s_red[5 + q] + s_red[10 + q] + s_red[15 + q];
  }
}

// ---------------- Kernel 2: final reduction (double) + loss math -----------
__global__ __launch_bounds__(256) void finalize(
    const float* __restrict__ partials, float* __restrict__ out) {
  __shared__ double s_red[4 * 5];
  const int j = threadIdx.x;  // 256 threads
  const int lane = j & 63, wave = j >> 6;
  double acc[5];
#pragma unroll
  for (int q = 0; q < 5; ++q)
    acc[q] = (double)partials[q * NBLK + j] +
             (double)partials[q * NBLK + 256 + j];
#pragma unroll
  for (int q = 0; q < 5; ++q) {
    double s = acc[q];
#pragma unroll
    for (int off = 32; off > 0; off >>= 1) s += __shfl_down(s, off, 64);
    if (lane == 0) s_red[wave * 5 + q] = s;
  }
  __syncthreads();
  if (j == 0) {
    double sum[5];
#pragma unroll
    for (int q = 0; q < 5; ++q)
      sum[q] = s_red[q] + s_red[5 + q] + s_red[10 + q] + s_red[15 + q];
    const double n = (double)NTOT;
    const double ce = sum[0] / n;
    const double dice = 1.0 - (2.0 * sum[3] + 1e-6) / (sum[1] + sum[2] + 1e-6);
    const double boundary = sum[4] / n;
    out[0] = (float)(ce + dice + 0.1 * boundary);
    out[1] = (float)ce;
    out[2] = (float)dice;
    out[3] = (float)boundary;
  }
}

extern "C" void kernel_launch(void* const* d_in, const int* in_sizes, int n_in,
                              void* d_out, int out_size, void* d_ws,
                              size_t ws_size, hipStream_t stream) {
  const float* logits = (const float*)d_in[0];
  const float* target = (const float*)d_in[1];
  float* out = (float*)d_out;

  float* partials = (float*)d_ws;  // 5*512*4 = 10 KB

  fused_kernel<<<NBLK, 256, 0, stream>>>(logits, target, partials);
  finalize<<<1, 256, 0, stream>>>(partials, out);
}

// Round 5
// 66.892 us; speedup vs baseline: 1.1008x; 1.0131x over previous
//
#include <hip/hip_runtime.h>

#define BB 8
#define HH 256
#define WW 256
#define NTOT (BB * HH * WW)   // 524288
#define RPB 4                 // rows per block (round-0 geometry)
#define NBLK (BB * HH / RPB)  // 512 blocks
#define HALO 16               // halo rows above/below the block's 4 rows
#define WLEN (RPB + 2 * HALO) // 36-row window

// ---- Single fused kernel: LDS-staged window + EDT + elementwise -----------
// v5: R4's windowed-mask structure, but the 36-row target window and the
// block's 4 logits rows are staged into LDS with float4 loads (10 vmem
// instructions/thread vs R4's 44 scalar column-strided loads). Bytes fetched
// are unchanged; vmem instruction count and exposed cold-cache latency drop
// ~4x, with all global traffic issued in one burst at kernel entry.
// Exactness: in-window fg gives the exact vertical distance; an empty
// direction triggers a rare lazy serial walk beyond the window (P ~ 2^-17
// per column-direction). Window-empty columns walk BOTH directions covering
// the full column, so `nonempty` stays exact. Every value and fp32 add is
// bit-identical to rounds 0/4 (same partial slots, same finalize).
__global__ __launch_bounds__(256) void fused_kernel(
    const float* __restrict__ logits, const float* __restrict__ target,
    float* __restrict__ partials /* [5][NBLK] */) {
  __shared__ float s_t[WLEN][WW];      // 36 KB: target window rows
  __shared__ float s_x[RPB][WW];       // 4 KB: own logits rows
  __shared__ float s_g2[RPB][3 * WW];  // 12 KB: [pad | g2 | pad]
  __shared__ float s_red[4 * 5];
  __shared__ int s_im[4 * 2];  // per-wave {any, rmax}

  const int g = blockIdx.x;        // 0..511
  const int b = g >> 6;            // image
  const int i0 = (g & 63) * RPB;   // first row within image
  const int j = threadIdx.x;       // column
  const int lane = j & 63, wave = j >> 6;

  const float* timg = target + b * (HH * WW);
  const float* limg = logits + b * (HH * WW);
  const int base = i0 - HALO;  // window start row (may be negative)

  // ---- stage: 36 target rows + 4 logits rows, float4, one burst ----------
  // window: 36 rows x 64 quads = 2304 float4s; 256 threads x 9 each.
  // Out-of-image rows load a clamped row (safe); validity handled at mask
  // build via a block-uniform row-range check.
#pragma unroll
  for (int w = 0; w < 9; ++w) {
    const int idx = w * 256 + j;  // 0..2303
    const int k = idx >> 6;       // window row 0..35
    const int q = idx & 63;       // quad within row
    const int rc = min(max(base + k, 0), HH - 1);
    const float4 v = *reinterpret_cast<const float4*>(timg + rc * WW + q * 4);
    *reinterpret_cast<float4*>(&s_t[k][q * 4]) = v;
  }
  {
    const int k = j >> 6;  // 0..3
    const int q = j & 63;
    const float4 v =
        *reinterpret_cast<const float4*>(limg + (i0 + k) * WW + q * 4);
    *reinterpret_cast<float4*>(&s_x[k][q * 4]) = v;
  }
  __syncthreads();

  // ---- 64-bit fg mask for own column from the LDS window -----------------
  // s_t[k][j]: fixed k, lanes read consecutive columns -> conflict-free.
  unsigned long long w64 = 0ull;
#pragma unroll
  for (int k = 0; k < WLEN; ++k) {
    const int row = base + k;  // block-uniform validity
    if (row >= 0 && row < HH && s_t[k][j] > 0.5f) w64 |= (1ull << k);
  }

  // lazy exact fallbacks beyond the window (rare; per-thread serial walk)
  int fgDown = 1 << 20;   // first fg row below the window (huge if none)
  int fgUp = -(1 << 20);  // first fg row above the window (-huge if none)
  if ((w64 >> (RPB - 1 + HALO)) == 0ull) {  // no fg in [i0+3, window top]
    for (int row = i0 + RPB - 1 + HALO + 1; row < HH; ++row)
      if (timg[row * WW + j] > 0.5f) { fgDown = row; break; }
  }
  if ((w64 << (63 - HALO)) == 0ull) {       // no fg in [window bottom, i0]
    for (int row = i0 - HALO - 1; row >= 0; --row)
      if (timg[row * WW + j] > 0.5f) { fgUp = row; break; }
  }
  const bool found =
      (w64 != 0ull) || (fgDown < (1 << 19)) || (fgUp > -(1 << 19));

  // ---- vertical distances for own rows; sentinel pads; scan radius -------
  int rmax = 0;
#pragma unroll
  for (int r = 0; r < RPB; ++r) {
    const int i = i0 + r;
    const int p = r + HALO;  // compile-time bit position of row i
    const unsigned long long bd = w64 >> p;         // rows >= i
    const unsigned long long bu = w64 << (63 - p);  // rows <= i
    const int dUp = bd ? __builtin_ctzll(bd) : (fgDown - i);
    const int dDn = bu ? __builtin_clzll(bu) : (i - fgUp);
    const int d = min(dUp, dDn);
    s_g2[r][WW + j] = (d < 256) ? (float)(d * d) : 1.0e9f;
    s_g2[r][j] = 1.0e9f;           // left pad
    s_g2[r][2 * WW + j] = 1.0e9f;  // right pad
    rmax = max(rmax, min(d, 255));
  }

  const int wave_any = __any(found);
#pragma unroll
  for (int off = 32; off > 0; off >>= 1)
    rmax = max(rmax, __shfl_down(rmax, off, 64));
  if (lane == 0) { s_im[wave * 2] = wave_any; s_im[wave * 2 + 1] = rmax; }
  __syncthreads();
  const int nonempty = s_im[0] | s_im[2] | s_im[4] | s_im[6];
  const int R = max(max(s_im[1], s_im[3]), max(s_im[5], s_im[7]));

  // ---- per-row pruned exact horizontal min + fused elementwise -----------
  // (k=j gives dt2(j) <= g2(j) => any argmin k* has |j-k*| <= d_j <= R)
  float v0 = 0.f, v1 = 0.f, v2 = 0.f, v3 = 0.f, v4 = 0.f;
#pragma unroll
  for (int r = 0; r < RPB; ++r) {
    const float* gp = &s_g2[r][WW + j];
    float mn = gp[0];
    for (int dlt = 1; dlt <= R; ++dlt) {
      const float d2 = (float)(dlt * dlt);
      mn = fminf(mn, fminf(d2 + gp[dlt], d2 + gp[-dlt]));
    }
    const float dt = nonempty ? sqrtf(mn) : 0.0f;

    const float x = s_x[r][j];           // own logits from LDS
    float t = s_t[HALO + r][j];          // own target from LDS (same bits)
    t = fminf(fmaxf(t, 0.0f), 1.0f);
    const float e = __expf(-fabsf(x));
    const float inv = 1.0f / (1.0f + e);
    const float ce = fmaxf(x, 0.0f) + __logf(1.0f + e) - x * t;
    float p = (x >= 0.0f) ? inv : e * inv;  // sigmoid
    p = fminf(fmaxf(p, 1e-6f), 1.0f - 1e-6f);
    v0 += ce; v1 += p; v2 += t; v3 += p * t; v4 += p * dt;
  }

  // ---- block reduce (fp32) -> per-block partial stores (round-0 layout) --
  float v[5] = {v0, v1, v2, v3, v4};
#pragma unroll
  for (int q = 0; q < 5; ++q) {
    float s = v[q];
#pragma unroll
    for (int off = 32; off > 0; off >>= 1) s += __shfl_down(s, off, 64);
    if (lane == 0) s_red[wave * 5 + q] = s;
  }
  __syncthreads();
  if (j == 0) {
#pragma unroll
    for (int q = 0; q < 5; ++q)
      partials[q * NBLK + g] =
          s_red[q] + s_red[5 + q] + s_red[10 + q] + s_red[15 + q];
  }
}

// ---------------- Kernel 2: final reduction (double) + loss math -----------
__global__ __launch_bounds__(256) void finalize(
    const float* __restrict__ partials, float* __restrict__ out) {
  __shared__ double s_red[4 * 5];
  const int j = threadIdx.x;  // 256 threads
  const int lane = j & 63, wave = j >> 6;
  double acc[5];
#pragma unroll
  for (int q = 0; q < 5; ++q)
    acc[q] = (double)partials[q * NBLK + j] +
             (double)partials[q * NBLK + 256 + j];
#pragma unroll
  for (int q = 0; q < 5; ++q) {
    double s = acc[q];
#pragma unroll
    for (int off = 32; off > 0; off >>= 1) s += __shfl_down(s, off, 64);
    if (lane == 0) s_red[wave * 5 + q] = s;
  }
  __syncthreads();
  if (j == 0) {
    double sum[5];
#pragma unroll
    for (int q = 0; q < 5; ++q)
      sum[q] = s_red[q] + s_red[5 + q] + s_red[10 + q] + s_red[15 + q];
    const double n = (double)NTOT;
    const double ce = sum[0] / n;
    const double dice = 1.0 - (2.0 * sum[3] + 1e-6) / (sum[1] + sum[2] + 1e-6);
    const double boundary = sum[4] / n;
    out[0] = (float)(ce + dice + 0.1 * boundary);
    out[1] = (float)ce;
    out[2] = (float)dice;
    out[3] = (float)boundary;
  }
}

extern "C" void kernel_launch(void* const* d_in, const int* in_sizes, int n_in,
                              void* d_out, int out_size, void* d_ws,
                              size_t ws_size, hipStream_t stream) {
  const float* logits = (const float*)d_in[0];
  const float* target = (const float*)d_in[1];
  float* out = (float*)d_out;

  float* partials = (float*)d_ws;  // 5*512*4 = 10 KB

  fused_kernel<<<NBLK, 256, 0, stream>>>(logits, target, partials);
  finalize<<<1, 256, 0, stream>>>(partials, out);
}